// Round 9
// baseline (290.733 us; speedup 1.0000x reference)
//
#include <hip/hip_runtime.h>

// SimpleGraphSAGE on MI355X — round 9.
// dst = repeat(arange(N),16) -> node i's edges are src[16i..16i+16), deg==16.
//
// History: R1 85us/layer; R4 72 fused bf16; R6 split gather 70 standalone;
// R7 sorted gather 57 standalone; R8 fused+sorted 66/layer, 208 total.
// Gather wall: ~20 cyc/row/CU invariant (occupancy/packing/bytes-insensitive
// above ~6 blk/CU). R8 pays +9us over the wall: 4 blk/CU occupancy (33KB
// LDS) + 128 ds_read_b32 matmul staging.
// R9: pack LDS as bf16 PAIRS (one dword = features 2kk,2kk+1 per node):
// LDS 16.6KB -> 6 blk/CU; matmul LDS reads halve (64 b32); unpack is 2 VALU.

#define NN   100000
#define DEG  16
#define F    64
#define KDIM 128
#define KK2  (KDIM / 2)   // packed k-pairs
#define NPB  64           // nodes per block (256 threads, 4 waves)
#define STR  65           // LDS column stride (+1 pad)
#define JPW  16           // output columns per wave
#define EDG  (NN * DEG)

__device__ __forceinline__ ushort f2bf(float f) {        // RNE
    unsigned u = __float_as_uint(f);
    return (ushort)((u + 0x7fffu + ((u >> 16) & 1u)) >> 16);
}
__device__ __forceinline__ float bf2f(ushort u) {
    return __uint_as_float(((unsigned)u) << 16);
}

__global__ __launch_bounds__(256)
void cvt_f32_bf16(const float* __restrict__ in, ushort* __restrict__ out, int n4)
{
    int i = blockIdx.x * 256 + threadIdx.x;
    if (i < n4) {
        float4 v = ((const float4*)in)[i];
        ushort4 o;
        o.x = f2bf(v.x); o.y = f2bf(v.y); o.z = f2bf(v.z); o.w = f2bf(v.w);
        ((ushort4*)out)[i] = o;
    }
}

// Batcher odd-even mergesort, 16 keys, fully unrolled -> registers only.
__device__ __forceinline__ void ce(unsigned& a, unsigned& b) {
    const unsigned lo = min(a, b), hi = max(a, b); a = lo; b = hi;
}
__device__ __forceinline__ void sort16(unsigned s[16]) {
    #pragma unroll
    for (int p = 1; p < 16; p <<= 1) {
        #pragma unroll
        for (int k = p; k >= 1; k >>= 1) {
            #pragma unroll
            for (int j = k & (p - 1); j + k < 16; j += 2 * k) {
                #pragma unroll
                for (int i = 0; i < k; ++i) {
                    if (i + j + k < 16)
                        if ((i + j) / (2 * p) == (i + j + k) / (2 * p))
                            ce(s[i + j], s[i + j + k]);
                }
            }
        }
    }
}

// ---------------- fused layer: sorted gather + SGPR-W matmul ----------------
// buf2[kk][n]: bf16 pair, k=2kk in low 16, k=2kk+1 in high 16, node column n.
template<bool RELU, bool EMIT_F32>
__global__ __launch_bounds__(256, 6)
void sage_fused(const ushort* __restrict__ in_bf16,   // [NN,F]
                const float*  __restrict__ W,         // [KDIM,F]
                const float*  __restrict__ bias,      // [F]
                const int*    __restrict__ src,       // [EDG]
                float*        __restrict__ out_f32,   // if EMIT_F32
                ushort*       __restrict__ out_bf16)  // if !EMIT_F32
{
    __shared__ unsigned buf2[KK2][STR];   // 64 x 65 x 4B = 16.6 KB

    const int tid   = threadIdx.x;
    const int lane  = tid & 63;
    const int wave  = __builtin_amdgcn_readfirstlane(tid >> 6);
    const int node0 = blockIdx.x * NPB;

    // ---- Self staging: lanes 0..31 -> node 2m, lanes 32..63 -> node 2m+1.
    // Lane loads one uint (features 2kk,2kk+1) -> fully coalesced 256B/instr.
    {
        const int kk   = lane & 31;
        const int half = lane >> 5;
        #pragma unroll
        for (int m = 0; m < 8; ++m) {
            const int n    = wave * JPW + 2 * m + half;
            const int node = node0 + n;
            unsigned v = 0;
            if (node < NN)
                v = *(const unsigned*)(in_bf16 + (size_t)node * F + 2 * kk);
            buf2[kk][n] = v;   // bank = (kk + n) % 32: 2-way same-dword free
        }
    }

    // ---- Sorted gather: 8-lane group handles nodes n0loc, n0loc+1 ----
    {
        const int sub   = lane & 7;
        const int grp   = lane >> 3;
        const int n0loc = wave * JPW + grp * 2;
        const int n1loc = n0loc + 1;
        const int n0    = node0 + n0loc;
        const int n1    = node0 + n1loc;
        const bool v0   = n0 < NN, v1 = n1 < NN;

        unsigned s0[DEG], s1[DEG];
        {
            const int4* p0 = (const int4*)(src + (size_t)n0 * DEG);
            const int4* p1 = (const int4*)(src + (size_t)n1 * DEG);
            #pragma unroll
            for (int q = 0; q < 4; ++q) {
                const int4 a = v0 ? p0[q] : make_int4(0, 0, 0, 0);
                const int4 b = v1 ? p1[q] : make_int4(0, 0, 0, 0);
                s0[4*q+0] = a.x; s0[4*q+1] = a.y;
                s0[4*q+2] = a.z; s0[4*q+3] = a.w;
                s1[4*q+0] = b.x; s1[4*q+1] = b.y;
                s1[4*q+2] = b.z; s1[4*q+3] = b.w;
            }
        }
        sort16(s0);
        sort16(s1);

        float a0[8], a1[8];
        #pragma unroll
        for (int f = 0; f < 8; ++f) { a0[f] = 0.f; a1[f] = 0.f; }

        #pragma unroll
        for (int e = 0; e < DEG; e += 2) {
            const uint4 r00 = *(const uint4*)(in_bf16 + (size_t)s0[e]   * F + sub * 8);
            const uint4 r01 = *(const uint4*)(in_bf16 + (size_t)s0[e+1] * F + sub * 8);
            const uint4 r10 = *(const uint4*)(in_bf16 + (size_t)s1[e]   * F + sub * 8);
            const uint4 r11 = *(const uint4*)(in_bf16 + (size_t)s1[e+1] * F + sub * 8);
            #pragma unroll
            for (int t = 0; t < 4; ++t) {
                const unsigned w00 = (&r00.x)[t], w01 = (&r01.x)[t];
                const unsigned w10 = (&r10.x)[t], w11 = (&r11.x)[t];
                a0[2*t]   += __uint_as_float(w00 << 16);
                a0[2*t+1] += __uint_as_float(w00 & 0xffff0000u);
                a0[2*t]   += __uint_as_float(w01 << 16);
                a0[2*t+1] += __uint_as_float(w01 & 0xffff0000u);
                a1[2*t]   += __uint_as_float(w10 << 16);
                a1[2*t+1] += __uint_as_float(w10 & 0xffff0000u);
                a1[2*t]   += __uint_as_float(w11 << 16);
                a1[2*t+1] += __uint_as_float(w11 & 0xffff0000u);
            }
        }

        // Mean -> packed bf16 pairs; kk = 32 + 4*sub + fp.
        #pragma unroll
        for (int fp = 0; fp < 4; ++fp) {
            const unsigned q0 =
                (unsigned)f2bf(a0[2*fp]   * (1.0f / DEG)) |
                ((unsigned)f2bf(a0[2*fp+1] * (1.0f / DEG)) << 16);
            const unsigned q1 =
                (unsigned)f2bf(a1[2*fp]   * (1.0f / DEG)) |
                ((unsigned)f2bf(a1[2*fp+1] * (1.0f / DEG)) << 16);
            buf2[32 + 4 * sub + fp][n0loc] = q0;
            buf2[32 + 4 * sub + fp][n1loc] = q1;
        }
    }
    __syncthreads();

    // ---- Matmul: lane = node, wave owns j in [16w,16w+16) ----
    const int j0 = wave * JPW;
    float acc[JPW];
    #pragma unroll
    for (int j = 0; j < JPW; ++j) acc[j] = bias[j0 + j];   // s_load

    #pragma unroll 2
    for (int kk = 0; kk < KK2; ++kk) {
        const unsigned d = buf2[kk][lane];        // ds_read_b32, conflict-free
        const float vlo = __uint_as_float(d << 16);
        const float vhi = __uint_as_float(d & 0xffff0000u);
        const float* Wlo = W + (2 * kk)     * F + j0;   // wave-uniform s_load
        const float* Whi = W + (2 * kk + 1) * F + j0;
        #pragma unroll
        for (int j = 0; j < JPW; ++j) {
            acc[j] = fmaf(vlo, Wlo[j], acc[j]);
            acc[j] = fmaf(vhi, Whi[j], acc[j]);
        }
    }

    const int node = node0 + lane;
    if (node < NN) {
        if (RELU) {
            #pragma unroll
            for (int j = 0; j < JPW; ++j) acc[j] = fmaxf(acc[j], 0.f);
        }
        if (EMIT_F32) {
            float4* op = (float4*)(out_f32 + node * F + j0);
            #pragma unroll
            for (int t = 0; t < 4; ++t)
                op[t] = make_float4(acc[4 * t], acc[4 * t + 1],
                                    acc[4 * t + 2], acc[4 * t + 3]);
        } else {
            uint4 q0, q1;
            #pragma unroll
            for (int t = 0; t < 8; ++t)
                (t < 4 ? (&q0.x)[t] : (&q1.x)[t - 4]) =
                    (unsigned)f2bf(acc[2 * t]) |
                    ((unsigned)f2bf(acc[2 * t + 1]) << 16);
            uint4* ob = (uint4*)(out_bf16 + node * F + j0);  // 32B
            ob[0] = q0; ob[1] = q1;
        }
    }
}

// ---------------- fallback (round-3, all-fp32, fused) ----------------
template<bool RELU>
__global__ __launch_bounds__(256, 4)
void sage_layer_f32(const float* __restrict__ feat,
                    const float* __restrict__ W,
                    const float* __restrict__ bias,
                    const int*   __restrict__ src,
                    float*       __restrict__ out)
{
    __shared__ float buf[KDIM][STR];
    const int tid   = threadIdx.x;
    const int lane  = tid & 63;
    const int wave  = __builtin_amdgcn_readfirstlane(tid >> 6);
    const int node0 = blockIdx.x * NPB;

    #pragma unroll 2
    for (int m = 0; m < NPB / 4; ++m) {
        const int n    = wave * (NPB / 4) + m;
        const int node = node0 + n;
        if (node < NN) {
            buf[lane][n] = feat[node * F + lane];
            const int* sp = src + node * DEG;
            float s = 0.f;
            #pragma unroll
            for (int e = 0; e < DEG; ++e) s += feat[sp[e] * F + lane];
            buf[F + lane][n] = s * (1.0f / DEG);
        }
    }
    __syncthreads();

    const int j0 = wave * JPW;
    float acc[JPW];
    #pragma unroll
    for (int j = 0; j < JPW; ++j) acc[j] = bias[j0 + j];
    #pragma unroll 4
    for (int k = 0; k < KDIM; ++k) {
        const float v = buf[k][lane];
        const float* Wr = W + k * F + j0;
        #pragma unroll
        for (int j = 0; j < JPW; ++j) acc[j] = fmaf(v, Wr[j], acc[j]);
    }
    const int node = node0 + lane;
    if (node < NN) {
        float4* op = (float4*)(out + node * F + j0);
        #pragma unroll
        for (int t = 0; t < 4; ++t) {
            float4 r = make_float4(acc[4 * t], acc[4 * t + 1],
                                   acc[4 * t + 2], acc[4 * t + 3]);
            if (RELU) {
                r.x = fmaxf(r.x, 0.f); r.y = fmaxf(r.y, 0.f);
                r.z = fmaxf(r.z, 0.f); r.w = fmaxf(r.w, 0.f);
            }
            op[t] = r;
        }
    }
}

extern "C" void kernel_launch(void* const* d_in, const int* in_sizes, int n_in,
                              void* d_out, int out_size, void* d_ws, size_t ws_size,
                              hipStream_t stream) {
    const float* x   = (const float*)d_in[0];
    const float* W1  = (const float*)d_in[1];
    const float* b1  = (const float*)d_in[2];
    const float* W2  = (const float*)d_in[3];
    const float* b2  = (const float*)d_in[4];
    const int*   src = (const int*)d_in[5];

    float* out = (float*)d_out;
    const int blocks = (NN + NPB - 1) / NPB;   // 1563

    const size_t hBF = (size_t)NN * F * sizeof(ushort);  // 12.8 MB

    if (ws_size >= 2 * hBF) {
        ushort* A = (ushort*)d_ws;                 // x_bf16
        ushort* B = (ushort*)((char*)d_ws + hBF);  // h_bf16

        const int n4 = NN * F / 4;
        cvt_f32_bf16<<<(n4 + 255) / 256, 256, 0, stream>>>(x, A, n4);
        sage_fused<true,  false><<<blocks, 256, 0, stream>>>(
            A, W1, b1, src, nullptr, B);           // layer1 -> h_bf16
        sage_fused<false, true ><<<blocks, 256, 0, stream>>>(
            B, W2, b2, src, out, nullptr);         // layer2 -> fp32 out
    } else {
        float* h = (float*)d_ws;
        sage_layer_f32<true ><<<blocks, 256, 0, stream>>>(x, W1, b1, src, h);
        sage_layer_f32<false><<<blocks, 256, 0, stream>>>(h, W2, b2, src, out);
    }
}

// Round 10
// 200.635 us; speedup vs baseline: 1.4491x; 1.4491x over previous
//
#include <hip/hip_runtime.h>

// SimpleGraphSAGE on MI355X — round 10.
// dst = repeat(arange(N),16) -> node i's edges are src[16i..16i+16), deg==16.
//
// History: R8 fused+sorted 66us/layer (33KB LDS, 4 blk/CU, VGPR 64).
// R9 packed-bf16 LDS (16.6KB) BUT __launch_bounds__(256,6) squeezed the
// register budget below the 32-VGPR sort arrays -> scratch spills
// (WRITE_SIZE 40->179MB, FETCH +90MB, dur 105us).
// R10 = R9 kernel with R8's budget: __launch_bounds__(256,4) -> VGPR cap
// 128 (expect ~64, no spill). Occupancy then set by resources: 16.6KB LDS
// allows 9 blk/CU, 64 VGPR allows 8 -> ~2x R8's residency for free.

#define NN   100000
#define DEG  16
#define F    64
#define KDIM 128
#define KK2  (KDIM / 2)   // packed k-pairs
#define NPB  64           // nodes per block (256 threads, 4 waves)
#define STR  65           // LDS column stride (+1 pad)
#define JPW  16           // output columns per wave
#define EDG  (NN * DEG)

__device__ __forceinline__ ushort f2bf(float f) {        // RNE
    unsigned u = __float_as_uint(f);
    return (ushort)((u + 0x7fffu + ((u >> 16) & 1u)) >> 16);
}
__device__ __forceinline__ float bf2f(ushort u) {
    return __uint_as_float(((unsigned)u) << 16);
}

__global__ __launch_bounds__(256)
void cvt_f32_bf16(const float* __restrict__ in, ushort* __restrict__ out, int n4)
{
    int i = blockIdx.x * 256 + threadIdx.x;
    if (i < n4) {
        float4 v = ((const float4*)in)[i];
        ushort4 o;
        o.x = f2bf(v.x); o.y = f2bf(v.y); o.z = f2bf(v.z); o.w = f2bf(v.w);
        ((ushort4*)out)[i] = o;
    }
}

// Batcher odd-even mergesort, 16 keys, fully unrolled -> registers only.
__device__ __forceinline__ void ce(unsigned& a, unsigned& b) {
    const unsigned lo = min(a, b), hi = max(a, b); a = lo; b = hi;
}
__device__ __forceinline__ void sort16(unsigned s[16]) {
    #pragma unroll
    for (int p = 1; p < 16; p <<= 1) {
        #pragma unroll
        for (int k = p; k >= 1; k >>= 1) {
            #pragma unroll
            for (int j = k & (p - 1); j + k < 16; j += 2 * k) {
                #pragma unroll
                for (int i = 0; i < k; ++i) {
                    if (i + j + k < 16)
                        if ((i + j) / (2 * p) == (i + j + k) / (2 * p))
                            ce(s[i + j], s[i + j + k]);
                }
            }
        }
    }
}

// ---------------- fused layer: sorted gather + SGPR-W matmul ----------------
// buf2[kk][n]: bf16 pair, k=2kk in low 16, k=2kk+1 in high 16, node column n.
template<bool RELU, bool EMIT_F32>
__global__ __launch_bounds__(256, 4)
void sage_fused(const ushort* __restrict__ in_bf16,   // [NN,F]
                const float*  __restrict__ W,         // [KDIM,F]
                const float*  __restrict__ bias,      // [F]
                const int*    __restrict__ src,       // [EDG]
                float*        __restrict__ out_f32,   // if EMIT_F32
                ushort*       __restrict__ out_bf16)  // if !EMIT_F32
{
    __shared__ unsigned buf2[KK2][STR];   // 64 x 65 x 4B = 16.6 KB

    const int tid   = threadIdx.x;
    const int lane  = tid & 63;
    const int wave  = __builtin_amdgcn_readfirstlane(tid >> 6);
    const int node0 = blockIdx.x * NPB;

    // ---- Self staging: lanes 0..31 -> node 2m, lanes 32..63 -> node 2m+1.
    // Lane loads one uint (features 2kk,2kk+1) -> fully coalesced 256B/instr.
    {
        const int kk   = lane & 31;
        const int half = lane >> 5;
        #pragma unroll
        for (int m = 0; m < 8; ++m) {
            const int n    = wave * JPW + 2 * m + half;
            const int node = node0 + n;
            unsigned v = 0;
            if (node < NN)
                v = *(const unsigned*)(in_bf16 + (size_t)node * F + 2 * kk);
            buf2[kk][n] = v;
        }
    }

    // ---- Sorted gather: 8-lane group handles nodes n0loc, n0loc+1 ----
    {
        const int sub   = lane & 7;
        const int grp   = lane >> 3;
        const int n0loc = wave * JPW + grp * 2;
        const int n1loc = n0loc + 1;
        const int n0    = node0 + n0loc;
        const int n1    = node0 + n1loc;
        const bool v0   = n0 < NN, v1 = n1 < NN;

        unsigned s0[DEG], s1[DEG];
        {
            const int4* p0 = (const int4*)(src + (size_t)n0 * DEG);
            const int4* p1 = (const int4*)(src + (size_t)n1 * DEG);
            #pragma unroll
            for (int q = 0; q < 4; ++q) {
                const int4 a = v0 ? p0[q] : make_int4(0, 0, 0, 0);
                const int4 b = v1 ? p1[q] : make_int4(0, 0, 0, 0);
                s0[4*q+0] = a.x; s0[4*q+1] = a.y;
                s0[4*q+2] = a.z; s0[4*q+3] = a.w;
                s1[4*q+0] = b.x; s1[4*q+1] = b.y;
                s1[4*q+2] = b.z; s1[4*q+3] = b.w;
            }
        }
        sort16(s0);
        sort16(s1);

        float a0[8], a1[8];
        #pragma unroll
        for (int f = 0; f < 8; ++f) { a0[f] = 0.f; a1[f] = 0.f; }

        #pragma unroll
        for (int e = 0; e < DEG; e += 2) {
            const uint4 r00 = *(const uint4*)(in_bf16 + (size_t)s0[e]   * F + sub * 8);
            const uint4 r01 = *(const uint4*)(in_bf16 + (size_t)s0[e+1] * F + sub * 8);
            const uint4 r10 = *(const uint4*)(in_bf16 + (size_t)s1[e]   * F + sub * 8);
            const uint4 r11 = *(const uint4*)(in_bf16 + (size_t)s1[e+1] * F + sub * 8);
            #pragma unroll
            for (int t = 0; t < 4; ++t) {
                const unsigned w00 = (&r00.x)[t], w01 = (&r01.x)[t];
                const unsigned w10 = (&r10.x)[t], w11 = (&r11.x)[t];
                a0[2*t]   += __uint_as_float(w00 << 16);
                a0[2*t+1] += __uint_as_float(w00 & 0xffff0000u);
                a0[2*t]   += __uint_as_float(w01 << 16);
                a0[2*t+1] += __uint_as_float(w01 & 0xffff0000u);
                a1[2*t]   += __uint_as_float(w10 << 16);
                a1[2*t+1] += __uint_as_float(w10 & 0xffff0000u);
                a1[2*t]   += __uint_as_float(w11 << 16);
                a1[2*t+1] += __uint_as_float(w11 & 0xffff0000u);
            }
        }

        // Mean -> packed bf16 pairs; kk = 32 + 4*sub + fp.
        #pragma unroll
        for (int fp = 0; fp < 4; ++fp) {
            const unsigned q0 =
                (unsigned)f2bf(a0[2*fp]   * (1.0f / DEG)) |
                ((unsigned)f2bf(a0[2*fp+1] * (1.0f / DEG)) << 16);
            const unsigned q1 =
                (unsigned)f2bf(a1[2*fp]   * (1.0f / DEG)) |
                ((unsigned)f2bf(a1[2*fp+1] * (1.0f / DEG)) << 16);
            buf2[32 + 4 * sub + fp][n0loc] = q0;
            buf2[32 + 4 * sub + fp][n1loc] = q1;
        }
    }
    __syncthreads();

    // ---- Matmul: lane = node, wave owns j in [16w,16w+16) ----
    const int j0 = wave * JPW;
    float acc[JPW];
    #pragma unroll
    for (int j = 0; j < JPW; ++j) acc[j] = bias[j0 + j];   // s_load

    #pragma unroll 2
    for (int kk = 0; kk < KK2; ++kk) {
        const unsigned d = buf2[kk][lane];        // ds_read_b32
        const float vlo = __uint_as_float(d << 16);
        const float vhi = __uint_as_float(d & 0xffff0000u);
        const float* Wlo = W + (2 * kk)     * F + j0;   // wave-uniform s_load
        const float* Whi = W + (2 * kk + 1) * F + j0;
        #pragma unroll
        for (int j = 0; j < JPW; ++j) {
            acc[j] = fmaf(vlo, Wlo[j], acc[j]);
            acc[j] = fmaf(vhi, Whi[j], acc[j]);
        }
    }

    const int node = node0 + lane;
    if (node < NN) {
        if (RELU) {
            #pragma unroll
            for (int j = 0; j < JPW; ++j) acc[j] = fmaxf(acc[j], 0.f);
        }
        if (EMIT_F32) {
            float4* op = (float4*)(out_f32 + node * F + j0);
            #pragma unroll
            for (int t = 0; t < 4; ++t)
                op[t] = make_float4(acc[4 * t], acc[4 * t + 1],
                                    acc[4 * t + 2], acc[4 * t + 3]);
        } else {
            uint4 q0, q1;
            #pragma unroll
            for (int t = 0; t < 8; ++t)
                (t < 4 ? (&q0.x)[t] : (&q1.x)[t - 4]) =
                    (unsigned)f2bf(acc[2 * t]) |
                    ((unsigned)f2bf(acc[2 * t + 1]) << 16);
            uint4* ob = (uint4*)(out_bf16 + node * F + j0);  // 32B
            ob[0] = q0; ob[1] = q1;
        }
    }
}

// ---------------- fallback (round-3, all-fp32, fused) ----------------
template<bool RELU>
__global__ __launch_bounds__(256, 4)
void sage_layer_f32(const float* __restrict__ feat,
                    const float* __restrict__ W,
                    const float* __restrict__ bias,
                    const int*   __restrict__ src,
                    float*       __restrict__ out)
{
    __shared__ float buf[KDIM][STR];
    const int tid   = threadIdx.x;
    const int lane  = tid & 63;
    const int wave  = __builtin_amdgcn_readfirstlane(tid >> 6);
    const int node0 = blockIdx.x * NPB;

    #pragma unroll 2
    for (int m = 0; m < NPB / 4; ++m) {
        const int n    = wave * (NPB / 4) + m;
        const int node = node0 + n;
        if (node < NN) {
            buf[lane][n] = feat[node * F + lane];
            const int* sp = src + node * DEG;
            float s = 0.f;
            #pragma unroll
            for (int e = 0; e < DEG; ++e) s += feat[sp[e] * F + lane];
            buf[F + lane][n] = s * (1.0f / DEG);
        }
    }
    __syncthreads();

    const int j0 = wave * JPW;
    float acc[JPW];
    #pragma unroll
    for (int j = 0; j < JPW; ++j) acc[j] = bias[j0 + j];
    #pragma unroll 4
    for (int k = 0; k < KDIM; ++k) {
        const float v = buf[k][lane];
        const float* Wr = W + k * F + j0;
        #pragma unroll
        for (int j = 0; j < JPW; ++j) acc[j] = fmaf(v, Wr[j], acc[j]);
    }
    const int node = node0 + lane;
    if (node < NN) {
        float4* op = (float4*)(out + node * F + j0);
        #pragma unroll
        for (int t = 0; t < 4; ++t) {
            float4 r = make_float4(acc[4 * t], acc[4 * t + 1],
                                   acc[4 * t + 2], acc[4 * t + 3]);
            if (RELU) {
                r.x = fmaxf(r.x, 0.f); r.y = fmaxf(r.y, 0.f);
                r.z = fmaxf(r.z, 0.f); r.w = fmaxf(r.w, 0.f);
            }
            op[t] = r;
        }
    }
}

extern "C" void kernel_launch(void* const* d_in, const int* in_sizes, int n_in,
                              void* d_out, int out_size, void* d_ws, size_t ws_size,
                              hipStream_t stream) {
    const float* x   = (const float*)d_in[0];
    const float* W1  = (const float*)d_in[1];
    const float* b1  = (const float*)d_in[2];
    const float* W2  = (const float*)d_in[3];
    const float* b2  = (const float*)d_in[4];
    const int*   src = (const int*)d_in[5];

    float* out = (float*)d_out;
    const int blocks = (NN + NPB - 1) / NPB;   // 1563

    const size_t hBF = (size_t)NN * F * sizeof(ushort);  // 12.8 MB

    if (ws_size >= 2 * hBF) {
        ushort* A = (ushort*)d_ws;                 // x_bf16
        ushort* B = (ushort*)((char*)d_ws + hBF);  // h_bf16

        const int n4 = NN * F / 4;
        cvt_f32_bf16<<<(n4 + 255) / 256, 256, 0, stream>>>(x, A, n4);
        sage_fused<true,  false><<<blocks, 256, 0, stream>>>(
            A, W1, b1, src, nullptr, B);           // layer1 -> h_bf16
        sage_fused<false, true ><<<blocks, 256, 0, stream>>>(
            B, W2, b2, src, out, nullptr);         // layer2 -> fp32 out
    } else {
        float* h = (float*)d_ws;
        sage_layer_f32<true ><<<blocks, 256, 0, stream>>>(x, W1, b1, src, h);
        sage_layer_f32<false><<<blocks, 256, 0, stream>>>(h, W2, b2, src, out);
    }
}

// Round 11
// 195.052 us; speedup vs baseline: 1.4905x; 1.0286x over previous
//
#include <hip/hip_runtime.h>

// SimpleGraphSAGE on MI355X — round 11.
// dst = repeat(arange(N),16) -> node i's edges are src[16i..16i+16), deg==16.
//
// History: R8 fused+sorted 66us/layer; R9 spill regression (launch_bounds
// too tight); R10 packed-LDS + (256,4): 61us/layer, 200.6 total.
// Cost model from R3/R6/R7/R10: ~20 cyc per distinct random row per CU
// (fixed) + ~2.5 cyc per 64B line. R11: fp8-e4m3 gather tables -> 64B rows
// (1 line). Self path made EXACT (layer1 self = fp32 x, LDS self half fp32)
// so the whole error budget goes to the fp8 neighbor-mean path
// (est absmax ~0.009 vs threshold 0.0188).

#define NN   100000
#define DEG  16
#define F    64
#define NPB  64           // nodes per block (256 threads, 4 waves)
#define STR  65           // LDS column stride (+1 pad)
#define JPW  16           // output columns per wave
#define EDG  (NN * DEG)

#if __has_builtin(__builtin_amdgcn_cvt_pk_f32_fp8) && __has_builtin(__builtin_amdgcn_cvt_pk_fp8_f32)
#define HW_FP8 1
#else
#define HW_FP8 0
#endif

typedef float v2f __attribute__((ext_vector_type(2)));

__device__ __forceinline__ ushort f2bf(float f) {        // RNE
    unsigned u = __float_as_uint(f);
    return (ushort)((u + 0x7fffu + ((u >> 16) & 1u)) >> 16);
}
__device__ __forceinline__ float bf2f(ushort u) {
    return __uint_as_float(((unsigned)u) << 16);
}

// ---- fp8 e4m3 helpers (HW path on gfx950; manual RNE fallback) ----
#if !HW_FP8
__device__ __forceinline__ unsigned fp8_enc1(float f) {  // e4m3fn RNE, saturating
    const unsigned u = __float_as_uint(f);
    const unsigned s = (u >> 31) << 7;
    const float af = fabsf(f);
    if (!(af < 448.f)) return s | 0x7E;                  // sat (also NaN->max)
    if (af < 0.015625f) {                                // subnormal, step 2^-9
        const int n = (int)rintf(af * 512.f);            // 0..8 (8 -> min normal)
        return s | (unsigned)n;
    }
    unsigned au = u & 0x7FFFFFFFu;
    const unsigned lsb = (au >> 20) & 1u;
    au += 0x7FFFFu + lsb;                                // RNE at bit 20
    const int e = (int)(au >> 23) - 127;
    if (e > 8) return s | 0x7E;
    return s | ((unsigned)(e + 7) << 3) | ((au >> 20) & 7u);
}
__device__ __forceinline__ float fp8_dec1(unsigned c) {
    const unsigned s = c >> 7;
    const int e = (int)((c >> 3) & 15u);
    const unsigned m = c & 7u;
    const float v = e ? ldexpf((float)(8 + m), e - 10) : ldexpf((float)m, -9);
    return s ? -v : v;
}
#endif

// pack 4 floats -> 4 fp8 bytes in one dword
__device__ __forceinline__ unsigned fp8_pack4(float a, float b, float c, float d) {
#if HW_FP8
    int t = __builtin_amdgcn_cvt_pk_fp8_f32(a, b, 0, false);
    t     = __builtin_amdgcn_cvt_pk_fp8_f32(c, d, t, true);
    return (unsigned)t;
#else
    return fp8_enc1(a) | (fp8_enc1(b) << 8) | (fp8_enc1(c) << 16) | (fp8_enc1(d) << 24);
#endif
}

// accumulate 4 fp8 bytes (one dword) into acc[0..3]
__device__ __forceinline__ void fp8_acc4(unsigned d, float* acc) {
#if HW_FP8
    const v2f lo = __builtin_amdgcn_cvt_pk_f32_fp8((int)d, false);
    const v2f hi = __builtin_amdgcn_cvt_pk_f32_fp8((int)d, true);
    acc[0] += lo.x; acc[1] += lo.y; acc[2] += hi.x; acc[3] += hi.y;
#else
    acc[0] += fp8_dec1(d & 0xffu);
    acc[1] += fp8_dec1((d >> 8) & 0xffu);
    acc[2] += fp8_dec1((d >> 16) & 0xffu);
    acc[3] += fp8_dec1(d >> 24);
#endif
}

// x (fp32) -> fp8 gather table
__global__ __launch_bounds__(256)
void cvt_f32_fp8(const float* __restrict__ in, unsigned* __restrict__ out, int n4)
{
    int i = blockIdx.x * 256 + threadIdx.x;
    if (i < n4) {
        float4 v = ((const float4*)in)[i];
        out[i] = fp8_pack4(v.x, v.y, v.z, v.w);
    }
}

// Batcher odd-even mergesort, 16 keys, fully unrolled -> registers only.
__device__ __forceinline__ void ce(unsigned& a, unsigned& b) {
    const unsigned lo = min(a, b), hi = max(a, b); a = lo; b = hi;
}
__device__ __forceinline__ void sort16(unsigned s[16]) {
    #pragma unroll
    for (int p = 1; p < 16; p <<= 1) {
        #pragma unroll
        for (int k = p; k >= 1; k >>= 1) {
            #pragma unroll
            for (int j = k & (p - 1); j + k < 16; j += 2 * k) {
                #pragma unroll
                for (int i = 0; i < k; ++i) {
                    if (i + j + k < 16)
                        if ((i + j) / (2 * p) == (i + j + k) / (2 * p))
                            ce(s[i + j], s[i + j + k]);
                }
            }
        }
    }
}

// ---------------- fused layer: sorted fp8 gather + SGPR-W matmul ----------------
// bufA[f][n]: fp32 self features (exact path).
// bufB[kk][n]: neighbor-mean bf16 pair (features 2kk,2kk+1 of the mean half).
template<bool RELU, bool SELF_F32, bool EMIT_F32>
__global__ __launch_bounds__(256, 4)
void sage_fused(const float*  __restrict__ selfA,      // [NN,F] fp32 (if SELF_F32)
                const ushort* __restrict__ selfB,      // [NN,F] bf16 (else)
                const unsigned char* __restrict__ gat, // [NN,F] fp8 table
                const float*  __restrict__ W,          // [2F,F]
                const float*  __restrict__ bias,       // [F]
                const int*    __restrict__ src,        // [EDG]
                float*        __restrict__ out_f32,    // if EMIT_F32
                ushort*       __restrict__ out_bf16,   // else: h table (self)
                unsigned char* __restrict__ out_fp8)   // else: h table (gather)
{
    __shared__ float    bufA[F][STR];        // 16.64 KB
    __shared__ unsigned bufB[F / 2][STR];    //  8.32 KB   (25 KB total)

    const int tid   = threadIdx.x;
    const int lane  = tid & 63;
    const int wave  = __builtin_amdgcn_readfirstlane(tid >> 6);
    const int node0 = blockIdx.x * NPB;

    // ---- Self staging: lane = feature, wave stages its 16 nodes ----
    #pragma unroll 4
    for (int m = 0; m < JPW; ++m) {
        const int n    = wave * JPW + m;
        const int node = node0 + n;
        float v = 0.f;
        if (node < NN)
            v = SELF_F32 ? selfA[(size_t)node * F + lane]
                         : bf2f(selfB[(size_t)node * F + lane]);
        bufA[lane][n] = v;
    }

    // ---- Sorted fp8 gather: 8-lane group handles nodes n0loc, n0loc+1 ----
    {
        const int sub   = lane & 7;          // features 8*sub .. 8*sub+7
        const int grp   = lane >> 3;
        const int n0loc = wave * JPW + grp * 2;
        const int n1loc = n0loc + 1;
        const int n0    = node0 + n0loc;
        const int n1    = node0 + n1loc;
        const bool v0   = n0 < NN, v1 = n1 < NN;

        unsigned s0[DEG], s1[DEG];
        {
            const int4* p0 = (const int4*)(src + (size_t)n0 * DEG);
            const int4* p1 = (const int4*)(src + (size_t)n1 * DEG);
            #pragma unroll
            for (int q = 0; q < 4; ++q) {
                const int4 a = v0 ? p0[q] : make_int4(0, 0, 0, 0);
                const int4 b = v1 ? p1[q] : make_int4(0, 0, 0, 0);
                s0[4*q+0] = a.x; s0[4*q+1] = a.y;
                s0[4*q+2] = a.z; s0[4*q+3] = a.w;
                s1[4*q+0] = b.x; s1[4*q+1] = b.y;
                s1[4*q+2] = b.z; s1[4*q+3] = b.w;
            }
        }
        sort16(s0);
        sort16(s1);

        float a0[8], a1[8];
        #pragma unroll
        for (int f = 0; f < 8; ++f) { a0[f] = 0.f; a1[f] = 0.f; }

        #pragma unroll
        for (int e = 0; e < DEG; e += 2) {
            // 64B fp8 rows: 8 lanes x uint2 (8B) each.
            const uint2 r00 = *(const uint2*)(gat + (size_t)s0[e]   * F + sub * 8);
            const uint2 r01 = *(const uint2*)(gat + (size_t)s0[e+1] * F + sub * 8);
            const uint2 r10 = *(const uint2*)(gat + (size_t)s1[e]   * F + sub * 8);
            const uint2 r11 = *(const uint2*)(gat + (size_t)s1[e+1] * F + sub * 8);
            fp8_acc4(r00.x, a0);     fp8_acc4(r00.y, a0 + 4);
            fp8_acc4(r01.x, a0);     fp8_acc4(r01.y, a0 + 4);
            fp8_acc4(r10.x, a1);     fp8_acc4(r10.y, a1 + 4);
            fp8_acc4(r11.x, a1);     fp8_acc4(r11.y, a1 + 4);
        }

        // Mean -> packed bf16 pairs; kk = 4*sub + fp (features 8sub+2fp, +1).
        #pragma unroll
        for (int fp = 0; fp < 4; ++fp) {
            const unsigned q0 =
                (unsigned)f2bf(a0[2*fp]   * (1.0f / DEG)) |
                ((unsigned)f2bf(a0[2*fp+1] * (1.0f / DEG)) << 16);
            const unsigned q1 =
                (unsigned)f2bf(a1[2*fp]   * (1.0f / DEG)) |
                ((unsigned)f2bf(a1[2*fp+1] * (1.0f / DEG)) << 16);
            bufB[4 * sub + fp][n0loc] = q0;
            bufB[4 * sub + fp][n1loc] = q1;
        }
    }
    __syncthreads();

    // ---- Matmul: lane = node, wave owns j in [16w,16w+16) ----
    const int j0 = wave * JPW;
    float acc[JPW];
    #pragma unroll
    for (int j = 0; j < JPW; ++j) acc[j] = bias[j0 + j];   // s_load

    // Self half (fp32 LDS, exact)
    #pragma unroll 4
    for (int k = 0; k < F; ++k) {
        const float v = bufA[k][lane];           // ds_read_b32, 2-way = free
        const float* Wr = W + k * F + j0;        // wave-uniform -> s_load
        #pragma unroll
        for (int j = 0; j < JPW; ++j)
            acc[j] = fmaf(v, Wr[j], acc[j]);
    }
    // Neighbor half (packed bf16 pairs)
    #pragma unroll 2
    for (int kk = 0; kk < F / 2; ++kk) {
        const unsigned d = bufB[kk][lane];
        const float vlo = __uint_as_float(d << 16);
        const float vhi = __uint_as_float(d & 0xffff0000u);
        const float* Wlo = W + (F + 2 * kk)     * F + j0;
        const float* Whi = W + (F + 2 * kk + 1) * F + j0;
        #pragma unroll
        for (int j = 0; j < JPW; ++j) {
            acc[j] = fmaf(vlo, Wlo[j], acc[j]);
            acc[j] = fmaf(vhi, Whi[j], acc[j]);
        }
    }

    const int node = node0 + lane;
    if (node < NN) {
        if (RELU) {
            #pragma unroll
            for (int j = 0; j < JPW; ++j) acc[j] = fmaxf(acc[j], 0.f);
        }
        if (EMIT_F32) {
            float4* op = (float4*)(out_f32 + (size_t)node * F + j0);
            #pragma unroll
            for (int t = 0; t < 4; ++t)
                op[t] = make_float4(acc[4 * t], acc[4 * t + 1],
                                    acc[4 * t + 2], acc[4 * t + 3]);
        } else {
            // h tables: bf16 (self path of layer 2) + fp8 (gather table)
            uint4 q0, q1;
            #pragma unroll
            for (int t = 0; t < 8; ++t)
                (t < 4 ? (&q0.x)[t] : (&q1.x)[t - 4]) =
                    (unsigned)f2bf(acc[2 * t]) |
                    ((unsigned)f2bf(acc[2 * t + 1]) << 16);
            uint4* ob = (uint4*)(out_bf16 + (size_t)node * F + j0);
            ob[0] = q0; ob[1] = q1;

            uint4 p;
            #pragma unroll
            for (int t = 0; t < 4; ++t)
                (&p.x)[t] = fp8_pack4(acc[4*t], acc[4*t+1], acc[4*t+2], acc[4*t+3]);
            *(uint4*)(out_fp8 + (size_t)node * F + j0) = p;
        }
    }
}

// ---------------- fallback (round-3, all-fp32, fused) ----------------
template<bool RELU>
__global__ __launch_bounds__(256, 4)
void sage_layer_f32(const float* __restrict__ feat,
                    const float* __restrict__ W,
                    const float* __restrict__ bias,
                    const int*   __restrict__ src,
                    float*       __restrict__ out)
{
    __shared__ float buf[2 * F][STR];
    const int tid   = threadIdx.x;
    const int lane  = tid & 63;
    const int wave  = __builtin_amdgcn_readfirstlane(tid >> 6);
    const int node0 = blockIdx.x * NPB;

    #pragma unroll 2
    for (int m = 0; m < NPB / 4; ++m) {
        const int n    = wave * (NPB / 4) + m;
        const int node = node0 + n;
        if (node < NN) {
            buf[lane][n] = feat[node * F + lane];
            const int* sp = src + node * DEG;
            float s = 0.f;
            #pragma unroll
            for (int e = 0; e < DEG; ++e) s += feat[sp[e] * F + lane];
            buf[F + lane][n] = s * (1.0f / DEG);
        }
    }
    __syncthreads();

    const int j0 = wave * JPW;
    float acc[JPW];
    #pragma unroll
    for (int j = 0; j < JPW; ++j) acc[j] = bias[j0 + j];
    #pragma unroll 4
    for (int k = 0; k < 2 * F; ++k) {
        const float v = buf[k][lane];
        const float* Wr = W + k * F + j0;
        #pragma unroll
        for (int j = 0; j < JPW; ++j) acc[j] = fmaf(v, Wr[j], acc[j]);
    }
    const int node = node0 + lane;
    if (node < NN) {
        float4* op = (float4*)(out + node * F + j0);
        #pragma unroll
        for (int t = 0; t < 4; ++t) {
            float4 r = make_float4(acc[4 * t], acc[4 * t + 1],
                                   acc[4 * t + 2], acc[4 * t + 3]);
            if (RELU) {
                r.x = fmaxf(r.x, 0.f); r.y = fmaxf(r.y, 0.f);
                r.z = fmaxf(r.z, 0.f); r.w = fmaxf(r.w, 0.f);
            }
            op[t] = r;
        }
    }
}

extern "C" void kernel_launch(void* const* d_in, const int* in_sizes, int n_in,
                              void* d_out, int out_size, void* d_ws, size_t ws_size,
                              hipStream_t stream) {
    const float* x   = (const float*)d_in[0];
    const float* W1  = (const float*)d_in[1];
    const float* b1  = (const float*)d_in[2];
    const float* W2  = (const float*)d_in[3];
    const float* b2  = (const float*)d_in[4];
    const int*   src = (const int*)d_in[5];

    float* out = (float*)d_out;
    const int blocks = (NN + NPB - 1) / NPB;   // 1563

    const size_t hFP8 = (size_t)NN * F;                   //  6.4 MB
    const size_t hBF  = (size_t)NN * F * sizeof(ushort);  // 12.8 MB

    if (ws_size >= 2 * hFP8 + hBF) {
        unsigned char* x_fp8 = (unsigned char*)d_ws;
        ushort*        h_bf  = (ushort*)((char*)d_ws + hFP8);
        unsigned char* h_fp8 = (unsigned char*)d_ws + hFP8 + hBF;

        const int n4 = NN * F / 4;
        cvt_f32_fp8<<<(n4 + 255) / 256, 256, 0, stream>>>(x, (unsigned*)x_fp8, n4);
        sage_fused<true,  true,  false><<<blocks, 256, 0, stream>>>(
            x, nullptr, x_fp8, W1, b1, src, nullptr, h_bf, h_fp8);
        sage_fused<false, false, true ><<<blocks, 256, 0, stream>>>(
            nullptr, h_bf, h_fp8, W2, b2, src, out, nullptr, nullptr);
    } else {
        float* h = (float*)d_ws;
        sage_layer_f32<true ><<<blocks, 256, 0, stream>>>(x, W1, b1, src, h);
        sage_layer_f32<false><<<blocks, 256, 0, stream>>>(h, W2, b2, src, out);
    }
}